// Round 1
// baseline (8632.846 us; speedup 1.0000x reference)
//
#include <hip/hip_runtime.h>

// Problem: B=4, T=4096, D=1024, A=1024
// in[0] = embedded fp32 [B,T,D]; in[1..3] = Wq,Wk,Wv fp32 [A,D]
// out = fp32 [B,T,A]
// ws layout: Q bf16 [16384,1024] | K bf16 | V bf16  (total ~101 MB)

#define T_SEQ 4096
#define DA    1024
#define BATCH 4
#define M_TOT (BATCH * T_SEQ)   // 16384

typedef float  f32x4  __attribute__((ext_vector_type(4)));
typedef short  bf16x8 __attribute__((ext_vector_type(8)));

static __device__ __forceinline__ unsigned short f2bf(float f) {
    unsigned u = __builtin_bit_cast(unsigned, f);
    u += 0x7FFFu + ((u >> 16) & 1u);          // round-to-nearest-even
    return (unsigned short)(u >> 16);
}
static __device__ __forceinline__ unsigned pack2(float a, float b) {
    return (unsigned)f2bf(a) | ((unsigned)f2bf(b) << 16);
}
static __device__ __forceinline__ float bflo(unsigned u) {
    return __builtin_bit_cast(float, u << 16);
}
static __device__ __forceinline__ float bfhi(unsigned u) {
    return __builtin_bit_cast(float, u & 0xFFFF0000u);
}

#define UNPACK8(dst, v)                                                     \
    {                                                                       \
        (dst)[0] = bflo((v).x); (dst)[1] = bfhi((v).x);                     \
        (dst)[2] = bflo((v).y); (dst)[3] = bfhi((v).y);                     \
        (dst)[4] = bflo((v).z); (dst)[5] = bfhi((v).z);                     \
        (dst)[6] = bflo((v).w); (dst)[7] = bfhi((v).w);                     \
    }

// ---------------------------------------------------------------------------
// Kernel 1: Y[m][n] = sum_d X[m][d] * W[n][d]   (Y bf16, 128x128 tile, MFMA)
// grid = (A/128, M/128), block = 256 (4 waves, 2x2 of 64x64)
// LDS row stride 40 bf16 (=80 B, 16B-aligned, 2-way bank aliasing only)
// ---------------------------------------------------------------------------
__global__ __launch_bounds__(256) void qkv_gemm(
    const float* __restrict__ X, const float* __restrict__ W,
    unsigned short* __restrict__ Y)
{
    __shared__ unsigned short Xs[128 * 40];
    __shared__ unsigned short Ws[128 * 40];

    const int tid  = threadIdx.x;
    const int m0   = blockIdx.y * 128;
    const int n0   = blockIdx.x * 128;
    const int wave = tid >> 6;
    const int lane = tid & 63;
    const int wm   = wave >> 1;      // 0..1
    const int wn   = wave & 1;       // 0..1
    const int q    = lane >> 4;      // 0..3
    const int r    = lane & 15;      // 0..15

    f32x4 acc[4][4];
    #pragma unroll
    for (int i = 0; i < 4; ++i)
        #pragma unroll
        for (int j = 0; j < 4; ++j)
            acc[i][j] = f32x4{0.f, 0.f, 0.f, 0.f};

    const int sr = tid >> 3;        // 0..31
    const int sc = (tid & 7) * 4;   // 0,4,...,28

    for (int k0 = 0; k0 < DA; k0 += 32) {
        #pragma unroll
        for (int p = 0; p < 4; ++p) {
            const int row = sr + p * 32;
            const float4 xv = *(const float4*)(X + (m0 + row) * DA + k0 + sc);
            const float4 wv = *(const float4*)(W + (n0 + row) * DA + k0 + sc);
            uint2 xp, wp;
            xp.x = pack2(xv.x, xv.y); xp.y = pack2(xv.z, xv.w);
            wp.x = pack2(wv.x, wv.y); wp.y = pack2(wv.z, wv.w);
            *(uint2*)&Xs[row * 40 + sc] = xp;
            *(uint2*)&Ws[row * 40 + sc] = wp;
        }
        __syncthreads();

        bf16x8 a[4], b[4];
        #pragma unroll
        for (int i = 0; i < 4; ++i)
            a[i] = *(const bf16x8*)&Xs[(wm * 64 + i * 16 + r) * 40 + q * 8];
        #pragma unroll
        for (int j = 0; j < 4; ++j)
            b[j] = *(const bf16x8*)&Ws[(wn * 64 + j * 16 + r) * 40 + q * 8];

        #pragma unroll
        for (int i = 0; i < 4; ++i)
            #pragma unroll
            for (int j = 0; j < 4; ++j)
                acc[i][j] = __builtin_amdgcn_mfma_f32_16x16x32_bf16(
                    a[i], b[j], acc[i][j], 0, 0, 0);
        __syncthreads();
    }

    // C/D layout: col = lane&15, row = (lane>>4)*4 + reg
    #pragma unroll
    for (int i = 0; i < 4; ++i)
        #pragma unroll
        for (int j = 0; j < 4; ++j)
            #pragma unroll
            for (int rr = 0; rr < 4; ++rr) {
                const int row = m0 + wm * 64 + i * 16 + q * 4 + rr;
                const int col = n0 + wn * 64 + j * 16 + r;
                Y[row * DA + col] = f2bf(acc[i][j][rr]);
            }
}

// ---------------------------------------------------------------------------
// Kernel 2: causal flash attention, one wave per query row.
// Lane owns a 16-element chunk of the 1024-dim head. Online softmax with
// wave-uniform rescale branch. grid = (T/4, B), block = 256 (4 waves).
// ---------------------------------------------------------------------------
__global__ __launch_bounds__(256) void attn(
    const unsigned short* __restrict__ Qb,
    const unsigned short* __restrict__ Kb,
    const unsigned short* __restrict__ Vb,
    float* __restrict__ out)
{
    const int lane = threadIdx.x & 63;
    const int wv   = threadIdx.x >> 6;

    // balance the causal triangle: pair block 2u with 2u+1 -> rows u / (N-1-u)
    const int u  = blockIdx.x >> 1;
    const int tg = (blockIdx.x & 1) ? (1023 - u) : u;
    const int t  = tg * 4 + wv;
    const int b  = blockIdx.y;

    const int rowbase = (b << 12) + t;          // b*T + t
    const unsigned short* qp = Qb + rowbase * DA + lane * 16;

    float qf[16], o[16];
    {
        const uint4 q0 = *(const uint4*)(qp);
        const uint4 q1 = *(const uint4*)(qp + 8);
        UNPACK8(qf, q0);
        UNPACK8((qf + 8), q1);
    }
    #pragma unroll
    for (int e = 0; e < 16; ++e) {
        qf[e] *= 0.03125f;   // fold 1/sqrt(1024) into q
        o[e] = 0.f;
    }

    float m = -INFINITY, l = 0.f;
    const unsigned short* kbase = Kb + (b << 12) * DA + lane * 16;
    const unsigned short* vbase = Vb + (b << 12) * DA + lane * 16;

    for (int j = 0; j <= t; ++j) {
        const uint4* kp = (const uint4*)(kbase + j * DA);
        const uint4 k0 = kp[0], k1 = kp[1];
        float kf[16];
        UNPACK8(kf, k0);
        UNPACK8((kf + 8), k1);

        float part = 0.f;
        #pragma unroll
        for (int e = 0; e < 16; ++e) part += qf[e] * kf[e];
        #pragma unroll
        for (int off = 32; off >= 1; off >>= 1)
            part += __shfl_xor(part, off, 64);
        const float s = part;                    // already scaled

        const uint4* vp = (const uint4*)(vbase + j * DA);
        const uint4 v0 = vp[0], v1 = vp[1];
        float vf[16];
        UNPACK8(vf, v0);
        UNPACK8((vf + 8), v1);

        if (s > m) {                             // wave-uniform branch
            const float alpha = __expf(m - s);   // exp(-inf)=0 on first iter
            m = s;
            l = l * alpha + 1.0f;                // p == 1 exactly
            #pragma unroll
            for (int e = 0; e < 16; ++e) o[e] = o[e] * alpha + vf[e];
        } else {
            const float p = __expf(s - m);
            l += p;
            #pragma unroll
            for (int e = 0; e < 16; ++e) o[e] += p * vf[e];
        }
    }

    const float inv = 1.0f / l;
    float* op = out + rowbase * DA + lane * 16;
    #pragma unroll
    for (int e = 0; e < 16; ++e) {
        const float x = o[e] * inv;
        op[e] = rintf(x * 1e4f) * 1e-4f;         // match round(out,4)
    }
}

// ---------------------------------------------------------------------------
extern "C" void kernel_launch(void* const* d_in, const int* in_sizes, int n_in,
                              void* d_out, int out_size, void* d_ws, size_t ws_size,
                              hipStream_t stream)
{
    const float* X  = (const float*)d_in[0];
    const float* Wq = (const float*)d_in[1];
    const float* Wk = (const float*)d_in[2];
    const float* Wv = (const float*)d_in[3];
    float* out = (float*)d_out;

    unsigned short* qb = (unsigned short*)d_ws;
    unsigned short* kb = qb + (size_t)M_TOT * DA;
    unsigned short* vb = kb + (size_t)M_TOT * DA;
    // requires ws_size >= 3 * 16384 * 1024 * 2 = 100,663,296 bytes

    dim3 ggrid(DA / 128, M_TOT / 128, 1);
    qkv_gemm<<<ggrid, 256, 0, stream>>>(X, Wq, qb);
    qkv_gemm<<<ggrid, 256, 0, stream>>>(X, Wk, kb);
    qkv_gemm<<<ggrid, 256, 0, stream>>>(X, Wv, vb);

    dim3 agrid(T_SEQ / 4, BATCH, 1);
    attn<<<agrid, 256, 0, stream>>>(qb, kb, vb, out);
}

// Round 2
// 1025.787 us; speedup vs baseline: 8.4158x; 8.4158x over previous
//
#include <hip/hip_runtime.h>

// B=4, T=4096, D=A=1024.
// Pipeline (all MFMA bf16):
//   1. Q = X·Wq^T, K = X·Wk^T          (bf16, [16384,1024])
//   2. Vt = (X·Wv^T)^T per batch        (bf16, [4][1024][4096])
//   3. per batch b: S = Q_b·K_b^T/32 (lower-tri blocks) -> softmax rows in
//      place (P bf16, zero-padded to 128-multiple) -> out_b = P·Vt_b^T (fp32,
//      rounded to 4 decimals)
// ws: Q 32MB | K 32MB | Vt 32MB | S/P 32MB (per-batch reuse) = 128 MB

#define T_SEQ 4096
#define DA    1024
#define BATCH 4
#define M_TOT (BATCH * T_SEQ)   // 16384

typedef float  f32x4  __attribute__((ext_vector_type(4)));
typedef short  bf16x8 __attribute__((ext_vector_type(8)));

static __device__ __forceinline__ unsigned short f2bf(float f) {
    unsigned u = __builtin_bit_cast(unsigned, f);
    u += 0x7FFFu + ((u >> 16) & 1u);          // RNE
    return (unsigned short)(u >> 16);
}
static __device__ __forceinline__ unsigned pack2(float a, float b) {
    return (unsigned)f2bf(a) | ((unsigned)f2bf(b) << 16);
}
static __device__ __forceinline__ float bflo(unsigned u) {
    return __builtin_bit_cast(float, u << 16);
}
static __device__ __forceinline__ float bfhi(unsigned u) {
    return __builtin_bit_cast(float, u & 0xFFFF0000u);
}
#define UNPACK8(dst, v)                                                     \
    {                                                                       \
        (dst)[0] = bflo((v).x); (dst)[1] = bfhi((v).x);                     \
        (dst)[2] = bflo((v).y); (dst)[3] = bfhi((v).y);                     \
        (dst)[4] = bflo((v).z); (dst)[5] = bfhi((v).z);                     \
        (dst)[6] = bflo((v).w); (dst)[7] = bfhi((v).w);                     \
    }

// ---------------------------------------------------------------------------
// Unified 128x128-tile MFMA GEMM:  Y[m][n] = scale * sum_k X[m][k]*W[n][k]
// F32IN: inputs fp32 (convert to bf16 while staging); else bf16 inputs.
// TRI:   early-exit blocks with blockIdx.x > blockIdx.y (causal lower-tri).
// VARK:  K_len = (blockIdx.y+1)*128 (causal K-range), else K_arg.
// EPI:   0 = bf16 row-major Y (ldy) | 1 = bf16 transposed per-batch
//        Vt[b][col][t] | 2 = fp32 Y rounded to 4 decimals (ldy).
// ---------------------------------------------------------------------------
template<bool F32IN, bool TRI, bool VARK, int EPI>
__global__ __launch_bounds__(256) void gemm128(
    const void* __restrict__ Xv, const void* __restrict__ Wmat,
    void* __restrict__ Yv, int ldx, int ldw, int ldy, int K_arg, float scale)
{
    if (TRI && blockIdx.x > blockIdx.y) return;
    const int K_len = VARK ? (int)(blockIdx.y + 1) * 128 : K_arg;

    __shared__ unsigned short Xs[128 * 40];
    __shared__ unsigned short Ws[128 * 40];

    const int tid  = threadIdx.x;
    const int m0   = blockIdx.y * 128;
    const int n0   = blockIdx.x * 128;
    const int wave = tid >> 6;
    const int lane = tid & 63;
    const int wm   = wave >> 1;
    const int wn   = wave & 1;
    const int qq   = lane >> 4;      // 0..3
    const int r    = lane & 15;      // 0..15

    f32x4 acc[4][4];
    #pragma unroll
    for (int i = 0; i < 4; ++i)
        #pragma unroll
        for (int j = 0; j < 4; ++j)
            acc[i][j] = f32x4{0.f, 0.f, 0.f, 0.f};

    const int sr = tid >> 3;        // f32 staging: 0..31
    const int sc = (tid & 7) * 4;
    const int r2 = tid >> 2;        // bf16 staging: 0..63
    const int c2 = (tid & 3) * 8;

    for (int k0 = 0; k0 < K_len; k0 += 32) {
        if (F32IN) {
            const float* X = (const float*)Xv;
            const float* W = (const float*)Wmat;
            #pragma unroll
            for (int p = 0; p < 4; ++p) {
                const int row = sr + p * 32;
                const float4 xv = *(const float4*)(X + (m0 + row) * ldx + k0 + sc);
                const float4 wv = *(const float4*)(W + (n0 + row) * ldw + k0 + sc);
                uint2 xp, wp;
                xp.x = pack2(xv.x, xv.y); xp.y = pack2(xv.z, xv.w);
                wp.x = pack2(wv.x, wv.y); wp.y = pack2(wv.z, wv.w);
                *(uint2*)&Xs[row * 40 + sc] = xp;
                *(uint2*)&Ws[row * 40 + sc] = wp;
            }
        } else {
            const unsigned short* X = (const unsigned short*)Xv;
            const unsigned short* W = (const unsigned short*)Wmat;
            #pragma unroll
            for (int p = 0; p < 2; ++p) {
                const int row = r2 + p * 64;
                *(uint4*)&Xs[row * 40 + c2] = *(const uint4*)(X + (m0 + row) * ldx + k0 + c2);
                *(uint4*)&Ws[row * 40 + c2] = *(const uint4*)(W + (n0 + row) * ldw + k0 + c2);
            }
        }
        __syncthreads();

        bf16x8 a[4], b[4];
        #pragma unroll
        for (int i = 0; i < 4; ++i)
            a[i] = *(const bf16x8*)&Xs[(wm * 64 + i * 16 + r) * 40 + qq * 8];
        #pragma unroll
        for (int j = 0; j < 4; ++j)
            b[j] = *(const bf16x8*)&Ws[(wn * 64 + j * 16 + r) * 40 + qq * 8];

        #pragma unroll
        for (int i = 0; i < 4; ++i)
            #pragma unroll
            for (int j = 0; j < 4; ++j)
                acc[i][j] = __builtin_amdgcn_mfma_f32_16x16x32_bf16(
                    a[i], b[j], acc[i][j], 0, 0, 0);
        __syncthreads();
    }

    // C/D layout: col = lane&15, row = (lane>>4)*4 + reg
    #pragma unroll
    for (int i = 0; i < 4; ++i)
        #pragma unroll
        for (int j = 0; j < 4; ++j)
            #pragma unroll
            for (int rr = 0; rr < 4; ++rr) {
                const int row = wm * 64 + i * 16 + qq * 4 + rr;
                const int col = wn * 64 + j * 16 + r;
                const float val = acc[i][j][rr] * scale;
                if (EPI == 0) {
                    ((unsigned short*)Yv)[(m0 + row) * ldy + (n0 + col)] = f2bf(val);
                } else if (EPI == 1) {
                    const int rg = m0 + row;          // global V row (b*T + t)
                    const int bb = rg >> 12;
                    const int tt = rg & 4095;
                    ((unsigned short*)Yv)[(bb << 22) + (n0 + col) * 4096 + tt] = f2bf(val);
                } else {
                    ((float*)Yv)[(m0 + row) * ldy + (n0 + col)] =
                        rintf(val * 1e4f) * 1e-4f;
                }
            }
}

// ---------------------------------------------------------------------------
// Row softmax in place on S (bf16, ld 4096). Row q valid for t in [0, q].
// Writes normalized P bf16 and zeros [q+1, roundup128(q+1)) so the variable-K
// GEMM reads exact probabilities.
// ---------------------------------------------------------------------------
__global__ __launch_bounds__(256) void softmax_rows(unsigned short* __restrict__ S)
{
    __shared__ float row[4096];
    __shared__ float red[4];
    const int q   = blockIdx.x;
    const int n   = q + 1;
    const int tid = threadIdx.x;
    const int n8  = n & ~7;
    unsigned short* rp = S + (size_t)q * 4096;

    for (int i0 = tid * 8; i0 < n8; i0 += 2048) {
        const uint4 v = *(const uint4*)(rp + i0);
        float f[8];
        UNPACK8(f, v);
        #pragma unroll
        for (int e = 0; e < 8; ++e) row[i0 + e] = f[e];
    }
    for (int i = n8 + tid; i < n; i += 256)
        row[i] = __builtin_bit_cast(float, (unsigned)rp[i] << 16);
    __syncthreads();

    float m = -1e30f;
    for (int i = tid; i < n; i += 256) m = fmaxf(m, row[i]);
    #pragma unroll
    for (int off = 32; off >= 1; off >>= 1) m = fmaxf(m, __shfl_xor(m, off, 64));
    if ((tid & 63) == 0) red[tid >> 6] = m;
    __syncthreads();
    m = fmaxf(fmaxf(red[0], red[1]), fmaxf(red[2], red[3]));
    __syncthreads();

    float s = 0.f;
    for (int i = tid; i < n; i += 256) {
        const float e = __expf(row[i] - m);
        row[i] = e;
        s += e;
    }
    #pragma unroll
    for (int off = 32; off >= 1; off >>= 1) s += __shfl_xor(s, off, 64);
    if ((tid & 63) == 0) red[tid >> 6] = s;
    __syncthreads();
    s = red[0] + red[1] + red[2] + red[3];
    const float inv = 1.f / s;

    const int npad = (n + 127) & ~127;
    for (int i = tid; i < n; i += 256) rp[i] = f2bf(row[i] * inv);
    for (int i = n + tid; i < npad; i += 256) rp[i] = 0;
}

// ---------------------------------------------------------------------------
extern "C" void kernel_launch(void* const* d_in, const int* in_sizes, int n_in,
                              void* d_out, int out_size, void* d_ws, size_t ws_size,
                              hipStream_t stream)
{
    const float* X  = (const float*)d_in[0];
    const float* Wq = (const float*)d_in[1];
    const float* Wk = (const float*)d_in[2];
    const float* Wv = (const float*)d_in[3];
    float* out = (float*)d_out;

    unsigned short* qb = (unsigned short*)d_ws;            // [16384,1024]
    unsigned short* kb = qb + (size_t)M_TOT * DA;          // [16384,1024]
    unsigned short* vt = kb + (size_t)M_TOT * DA;          // [4][1024][4096]
    unsigned short* sb = vt + (size_t)M_TOT * DA;          // [4096,4096] reused
    // ws needed: 4 * 16384*1024 * 2 B = 128 MB

    const dim3 gproj(DA / 128, M_TOT / 128);
    gemm128<true, false, false, 0><<<gproj, 256, 0, stream>>>(
        X, Wq, qb, DA, DA, DA, DA, 1.f);
    gemm128<true, false, false, 0><<<gproj, 256, 0, stream>>>(
        X, Wk, kb, DA, DA, DA, DA, 1.f);
    gemm128<true, false, false, 1><<<gproj, 256, 0, stream>>>(
        X, Wv, vt, DA, DA, 0, DA, 1.f);

    for (int b = 0; b < BATCH; ++b) {
        const unsigned short* Qb  = qb + (size_t)b * T_SEQ * DA;
        const unsigned short* Kb  = kb + (size_t)b * T_SEQ * DA;
        const unsigned short* Vtb = vt + (size_t)b * T_SEQ * DA;
        float* outb = out + (size_t)b * T_SEQ * DA;

        gemm128<false, true, false, 0><<<dim3(T_SEQ / 128, T_SEQ / 128), 256, 0, stream>>>(
            Qb, Kb, sb, DA, DA, T_SEQ, DA, 0.03125f);
        softmax_rows<<<T_SEQ, 256, 0, stream>>>(sb);
        gemm128<false, false, true, 2><<<dim3(DA / 128, T_SEQ / 128), 256, 0, stream>>>(
            sb, Vtb, outb, T_SEQ, T_SEQ, DA, 0, 1.f);
    }
}

// Round 3
// 746.868 us; speedup vs baseline: 11.5587x; 1.3735x over previous
//
#include <hip/hip_runtime.h>

// B=4, T=4096, D=A=1024.  All-MFMA pipeline, batch-fused:
//   proj (1 dispatch): Q,K bf16 row-major; V written transposed Vt[b][a][t]
//   s_gemm (1): packed lower-tri S = Q·K^T/32, all batches, big-K-first
//   softmax (1): in-place rows of packed S -> P bf16, zero-padded to ld
//   o_gemm (1): out = P·Vt^T, variable K, fp32 rounded to 4 decimals
// Packed S: row-block y (0..31) stored at block offset y(y+1)/2*128*128 with
// leading dim (y+1)*128  -> 17.3 MB/batch instead of 33.5.
// ws: Q 32MB | K 32MB | Vt 32MB | S G*17.3MB  (G = batches/group, from ws_size)

#define T_SEQ 4096
#define DA    1024
#define BATCH 4
#define M_TOT (BATCH * T_SEQ)            // 16384
#define SB_ELEMS 8650752                  // 528 blocks * 16384 elems (per batch)

typedef float  f32x4  __attribute__((ext_vector_type(4)));
typedef short  bf16x8 __attribute__((ext_vector_type(8)));

static __device__ __forceinline__ unsigned short f2bf(float f) {
    unsigned u = __builtin_bit_cast(unsigned, f);
    u += 0x7FFFu + ((u >> 16) & 1u);      // RNE
    return (unsigned short)(u >> 16);
}
static __device__ __forceinline__ unsigned pack2(float a, float b) {
    return (unsigned)f2bf(a) | ((unsigned)f2bf(b) << 16);
}
static __device__ __forceinline__ float bflo(unsigned u) {
    return __builtin_bit_cast(float, u << 16);
}
static __device__ __forceinline__ float bfhi(unsigned u) {
    return __builtin_bit_cast(float, u & 0xFFFF0000u);
}

// ---- shared GEMM building blocks -----------------------------------------
// Stage a 128x32 tile into LDS (row stride 40 elems = 80 B; uint4 writes land
// on bank-quads (5*row + c) mod 8 -> uniform, no conflicts).
// Each thread: r2 = tid>>2 (row 0..63, 2 passes), c2 = (tid&3)*8 (col).
template<bool F32>
static __device__ __forceinline__ void stage_tile(
    const void* __restrict__ X, int ldx, int m0, int k0,
    unsigned short* __restrict__ Xs, int r2, int c2)
{
    #pragma unroll
    for (int p = 0; p < 2; ++p) {
        const int row = r2 + p * 64;
        if (F32) {
            const float* Xf = (const float*)X + (size_t)(m0 + row) * ldx + k0 + c2;
            const float4 v0 = *(const float4*)(Xf);
            const float4 v1 = *(const float4*)(Xf + 4);
            uint4 pk;
            pk.x = pack2(v0.x, v0.y); pk.y = pack2(v0.z, v0.w);
            pk.z = pack2(v1.x, v1.y); pk.w = pack2(v1.z, v1.w);
            *(uint4*)&Xs[row * 40 + c2] = pk;
        } else {
            const unsigned short* Xb = (const unsigned short*)X;
            *(uint4*)&Xs[row * 40 + c2] =
                *(const uint4*)(Xb + (size_t)(m0 + row) * ldx + k0 + c2);
        }
    }
}

static __device__ __forceinline__ void mfma_tile(
    const unsigned short* __restrict__ Xs, const unsigned short* __restrict__ Ws,
    int wm, int wn, int qq, int r, f32x4 acc[4][4])
{
    bf16x8 a[4], b[4];
    #pragma unroll
    for (int i = 0; i < 4; ++i)
        a[i] = *(const bf16x8*)&Xs[(wm * 64 + i * 16 + r) * 40 + qq * 8];
    #pragma unroll
    for (int j = 0; j < 4; ++j)
        b[j] = *(const bf16x8*)&Ws[(wn * 64 + j * 16 + r) * 40 + qq * 8];
    #pragma unroll
    for (int i = 0; i < 4; ++i)
        #pragma unroll
        for (int j = 0; j < 4; ++j)
            acc[i][j] = __builtin_amdgcn_mfma_f32_16x16x32_bf16(
                a[i], b[j], acc[i][j], 0, 0, 0);
}

#define GEMM_PROLOGUE                                                        \
    __shared__ unsigned short Xs[128 * 40];                                  \
    __shared__ unsigned short Ws[128 * 40];                                  \
    const int tid  = threadIdx.x;                                            \
    const int wave = tid >> 6;                                               \
    const int lane = tid & 63;                                               \
    const int wm   = wave >> 1;                                              \
    const int wn   = wave & 1;                                               \
    const int qq   = lane >> 4;                                              \
    const int r    = lane & 15;                                              \
    const int r2   = tid >> 2;                                               \
    const int c2   = (tid & 3) * 8;                                          \
    f32x4 acc[4][4];                                                         \
    _Pragma("unroll")                                                        \
    for (int i = 0; i < 4; ++i)                                              \
        _Pragma("unroll")                                                    \
        for (int j = 0; j < 4; ++j)                                          \
            acc[i][j] = f32x4{0.f, 0.f, 0.f, 0.f};

// C/D layout: col = lane&15, row = (lane>>4)*4 + reg
#define EPILOGUE_LOOP(BODY)                                                  \
    _Pragma("unroll")                                                        \
    for (int i = 0; i < 4; ++i)                                              \
        _Pragma("unroll")                                                    \
        for (int j = 0; j < 4; ++j)                                          \
            _Pragma("unroll")                                                \
            for (int rr = 0; rr < 4; ++rr) {                                 \
                const int row = wm * 64 + i * 16 + qq * 4 + rr;              \
                const int col = wn * 64 + j * 16 + r;                        \
                const float val = acc[i][j][rr];                             \
                BODY                                                         \
            }

// ---------------------------------------------------------------------------
// Projections: grid (8, 128, 3). z=0 -> Q, z=1 -> K (row-major bf16),
// z=2 -> V transposed into Vt[b][a][t].
// ---------------------------------------------------------------------------
__global__ __launch_bounds__(256) void proj_gemm(
    const float* __restrict__ X, const float* __restrict__ Wq,
    const float* __restrict__ Wk, const float* __restrict__ Wv,
    unsigned short* __restrict__ qb, unsigned short* __restrict__ kb,
    unsigned short* __restrict__ vt)
{
    const int z = blockIdx.z;
    const float* W = (z == 0) ? Wq : (z == 1) ? Wk : Wv;
    const int m0 = blockIdx.y * 128;
    const int n0 = blockIdx.x * 128;
    GEMM_PROLOGUE
    for (int k0 = 0; k0 < DA; k0 += 32) {
        stage_tile<true>(X, DA, m0, k0, Xs, r2, c2);
        stage_tile<true>(W, DA, n0, k0, Ws, r2, c2);
        __syncthreads();
        mfma_tile(Xs, Ws, wm, wn, qq, r, acc);
        __syncthreads();
    }
    if (z < 2) {
        unsigned short* Y = z ? kb : qb;
        EPILOGUE_LOOP({
            Y[(size_t)(m0 + row) * DA + (n0 + col)] = f2bf(val);
        })
    } else {
        EPILOGUE_LOOP({
            const int rg = m0 + row;
            const int bb = rg >> 12;
            const int tt = rg & 4095;
            vt[((size_t)bb << 22) + (size_t)(n0 + col) * 4096 + tt] = f2bf(val);
        })
    }
}

// ---------------------------------------------------------------------------
// S = Q·K^T / 32, packed lower-tri, all batches. grid (32, 32, G).
// y remapped descending so expensive rows dispatch first.
// ---------------------------------------------------------------------------
__global__ __launch_bounds__(256) void s_gemm(
    const unsigned short* __restrict__ qb, const unsigned short* __restrict__ kb,
    unsigned short* __restrict__ sbuf, int bbase)
{
    const int y = 31 - (int)blockIdx.y;
    const int x = blockIdx.x;
    if (x > y) return;
    const int b = bbase + blockIdx.z;
    const unsigned short* Qb = qb + (size_t)b * T_SEQ * DA;
    const unsigned short* Kb = kb + (size_t)b * T_SEQ * DA;
    unsigned short* Sb = sbuf + (size_t)blockIdx.z * SB_ELEMS;
    const int m0 = y * 128;
    const int n0 = x * 128;
    GEMM_PROLOGUE
    for (int k0 = 0; k0 < DA; k0 += 32) {
        stage_tile<false>(Qb, DA, m0, k0, Xs, r2, c2);
        stage_tile<false>(Kb, DA, n0, k0, Ws, r2, c2);
        __syncthreads();
        mfma_tile(Xs, Ws, wm, wn, qq, r, acc);
        __syncthreads();
    }
    const int ld = (y + 1) * 128;
    unsigned short* base = Sb + (size_t)(y * (y + 1) / 2) * 16384;
    EPILOGUE_LOOP({
        base[(size_t)row * ld + (n0 + col)] = f2bf(val * 0.03125f);
    })
}

// ---------------------------------------------------------------------------
// Row softmax on packed S. grid (4096, G); big rows first.
// ---------------------------------------------------------------------------
__global__ __launch_bounds__(256) void softmax_rows(unsigned short* __restrict__ sbuf)
{
    __shared__ float row[4096];
    __shared__ float red[4];
    const int q   = 4095 - (int)blockIdx.x;
    const int n   = q + 1;
    const int tid = threadIdx.x;
    const int y   = q >> 7;
    const int ld  = (y + 1) * 128;
    unsigned short* rp = sbuf + (size_t)blockIdx.y * SB_ELEMS
                       + (size_t)(y * (y + 1) / 2) * 16384
                       + (size_t)(q & 127) * ld;
    const int n8 = n & ~7;

    for (int i0 = tid * 8; i0 < n8; i0 += 2048) {
        const uint4 v = *(const uint4*)(rp + i0);
        // two float4 stores -> bank-quads 2t and 2t+1, all 8 quads covered
        *(float4*)&row[i0]     = make_float4(bflo(v.x), bfhi(v.x), bflo(v.y), bfhi(v.y));
        *(float4*)&row[i0 + 4] = make_float4(bflo(v.z), bfhi(v.z), bflo(v.w), bfhi(v.w));
    }
    for (int i = n8 + tid; i < n; i += 256)
        row[i] = __builtin_bit_cast(float, (unsigned)rp[i] << 16);
    __syncthreads();

    float m = -1e30f;
    for (int i = tid; i < n; i += 256) m = fmaxf(m, row[i]);
    #pragma unroll
    for (int off = 32; off >= 1; off >>= 1) m = fmaxf(m, __shfl_xor(m, off, 64));
    if ((tid & 63) == 0) red[tid >> 6] = m;
    __syncthreads();
    m = fmaxf(fmaxf(red[0], red[1]), fmaxf(red[2], red[3]));
    __syncthreads();

    float s = 0.f;
    for (int i = tid; i < n; i += 256) {
        const float e = __expf(row[i] - m);
        row[i] = e;
        s += e;
    }
    #pragma unroll
    for (int off = 32; off >= 1; off >>= 1) s += __shfl_xor(s, off, 64);
    if ((tid & 63) == 0) red[tid >> 6] = s;
    __syncthreads();
    s = red[0] + red[1] + red[2] + red[3];
    const float inv = 1.f / s;

    for (int i0 = tid * 8; i0 < n8; i0 += 2048) {
        const float4 f0 = *(const float4*)&row[i0];
        const float4 f1 = *(const float4*)&row[i0 + 4];
        uint4 pk;
        pk.x = pack2(f0.x * inv, f0.y * inv);
        pk.y = pack2(f0.z * inv, f0.w * inv);
        pk.z = pack2(f1.x * inv, f1.y * inv);
        pk.w = pack2(f1.z * inv, f1.w * inv);
        *(uint4*)(rp + i0) = pk;
    }
    for (int i = n8 + tid; i < ld; i += 256)
        rp[i] = (i < n) ? f2bf(row[i] * inv) : (unsigned short)0;
}

// ---------------------------------------------------------------------------
// out = P·Vt^T, variable K = (y+1)*128. grid (8, 32, G), big-K first.
// ---------------------------------------------------------------------------
__global__ __launch_bounds__(256) void o_gemm(
    const unsigned short* __restrict__ sbuf, const unsigned short* __restrict__ vt,
    float* __restrict__ out, int bbase)
{
    const int y = 31 - (int)blockIdx.y;
    const int b = bbase + blockIdx.z;
    const int K_len = (y + 1) * 128;
    const unsigned short* A = sbuf + (size_t)blockIdx.z * SB_ELEMS
                            + (size_t)(y * (y + 1) / 2) * 16384;
    const unsigned short* Bv = vt + (size_t)b * T_SEQ * DA;  // [1024][4096]
    const int n0 = blockIdx.x * 128;
    GEMM_PROLOGUE
    for (int k0 = 0; k0 < K_len; k0 += 32) {
        stage_tile<false>(A, K_len, 0, k0, Xs, r2, c2);
        stage_tile<false>(Bv, T_SEQ, n0, k0, Ws, r2, c2);
        __syncthreads();
        mfma_tile(Xs, Ws, wm, wn, qq, r, acc);
        __syncthreads();
    }
    float* outb = out + (size_t)b * T_SEQ * DA + (size_t)y * 128 * DA;
    EPILOGUE_LOOP({
        outb[(size_t)row * DA + (n0 + col)] = rintf(val * 1e4f) * 1e-4f;
    })
}

// ---------------------------------------------------------------------------
extern "C" void kernel_launch(void* const* d_in, const int* in_sizes, int n_in,
                              void* d_out, int out_size, void* d_ws, size_t ws_size,
                              hipStream_t stream)
{
    const float* X  = (const float*)d_in[0];
    const float* Wq = (const float*)d_in[1];
    const float* Wk = (const float*)d_in[2];
    const float* Wv = (const float*)d_in[3];
    float* out = (float*)d_out;

    unsigned short* qb = (unsigned short*)d_ws;            // [16384,1024]
    unsigned short* kb = qb + (size_t)M_TOT * DA;
    unsigned short* vt = kb + (size_t)M_TOT * DA;          // [4][1024][4096]
    unsigned short* sbuf = vt + (size_t)M_TOT * DA;        // G * SB_ELEMS

    // group size by available workspace
    const size_t fixed = (size_t)3 * M_TOT * DA * 2;
    int G = 1;
    if (ws_size >= fixed + (size_t)4 * SB_ELEMS * 2) G = 4;
    else if (ws_size >= fixed + (size_t)2 * SB_ELEMS * 2) G = 2;

    proj_gemm<<<dim3(DA / 128, M_TOT / 128, 3), 256, 0, stream>>>(
        X, Wq, Wk, Wv, qb, kb, vt);

    for (int b0 = 0; b0 < BATCH; b0 += G) {
        s_gemm<<<dim3(32, 32, G), 256, 0, stream>>>(qb, kb, sbuf, b0);
        softmax_rows<<<dim3(4096, G), 256, 0, stream>>>(sbuf);
        o_gemm<<<dim3(8, 32, G), 256, 0, stream>>>(sbuf, vt, out, b0);
    }
}

// Round 4
// 565.854 us; speedup vs baseline: 15.2563x; 1.3199x over previous
//
#include <hip/hip_runtime.h>

// B=4, T=4096, D=A=1024.  All-MFMA bf16 pipeline, m97-style async staging:
//   to_bf16 : X,Wq,Wk,Wv fp32 -> bf16 (stored in d_out, dead until o_gemm)
//   proj    : Q,K bf16 row-major + V transposed Vt[b][a][t]; XCD-swizzled
//   s_gemm  : packed lower-tri S = Q.K^T/32 (all batches)
//   softmax : in-place rows of packed S -> P bf16, zero-padded to ld
//   o_gemm  : out = P.Vt^T, variable K, fp32 rounded to 4 decimals
// Packed S: row-block y at elem offset y(y+1)/2*16384, leading dim (y+1)*128.
// ws: Q 32MB | K 32MB | Vt 32MB | S G*17.3MB   (G from ws_size)
// d_out (64MB) doubles as Xb(32MB)+Wb(6MB) scratch during projection.

#define T_SEQ 4096
#define DA    1024
#define BATCH 4
#define M_TOT (BATCH * T_SEQ)            // 16384
#define SB_ELEMS 8650752                  // 528 tri-blocks * 16384 elems

typedef float  f32x4  __attribute__((ext_vector_type(4)));
typedef short  bf16x8 __attribute__((ext_vector_type(8)));

static __device__ __forceinline__ unsigned short f2bf(float f) {
    unsigned u = __builtin_bit_cast(unsigned, f);
    u += 0x7FFFu + ((u >> 16) & 1u);      // RNE
    return (unsigned short)(u >> 16);
}
static __device__ __forceinline__ unsigned pack2(float a, float b) {
    return (unsigned)f2bf(a) | ((unsigned)f2bf(b) << 16);
}
static __device__ __forceinline__ float bflo(unsigned u) {
    return __builtin_bit_cast(float, u << 16);
}
static __device__ __forceinline__ float bfhi(unsigned u) {
    return __builtin_bit_cast(float, u & 0xFFFF0000u);
}

// async global->LDS, 16 B per lane; LDS dest = wave-uniform base + lane*16
#define GLOAD_LDS16(g, l)                                                   \
    __builtin_amdgcn_global_load_lds(                                       \
        (const __attribute__((address_space(1))) void*)(g),                 \
        (__attribute__((address_space(3))) void*)(l), 16, 0, 0)

// ---------------------------------------------------------------------------
// m97-style K-loop: unpadded 128x32 bf16 tiles, async staging, 16 MFMA/iter.
// ---------------------------------------------------------------------------
static __device__ __forceinline__ void gemm_k_loop(
    const unsigned short* __restrict__ A, int lda,
    const unsigned short* __restrict__ B, int ldb,
    int m0, int n0, int K,
    unsigned short* __restrict__ Xs, unsigned short* __restrict__ Ws,
    int tid, int wm, int wn, int qq, int r, f32x4 acc[4][4])
{
    const int srow = tid >> 2;            // 0..63
    const int scol = (tid & 3) * 8;       // 0,8,16,24
    const unsigned short* ga0 = A + (size_t)(m0 + srow) * lda + scol;
    const unsigned short* ga1 = ga0 + (size_t)64 * lda;
    const unsigned short* gb0 = B + (size_t)(n0 + srow) * ldb + scol;
    const unsigned short* gb1 = gb0 + (size_t)64 * ldb;
    unsigned short* la0 = Xs + tid * 8;
    unsigned short* la1 = la0 + 2048;
    unsigned short* lb0 = Ws + tid * 8;
    unsigned short* lb1 = lb0 + 2048;

    for (int k0 = 0; k0 < K; k0 += 32) {
        GLOAD_LDS16(ga0, la0);
        GLOAD_LDS16(ga1, la1);
        GLOAD_LDS16(gb0, lb0);
        GLOAD_LDS16(gb1, lb1);
        ga0 += 32; ga1 += 32; gb0 += 32; gb1 += 32;
        __syncthreads();

        bf16x8 a[4], b[4];
        #pragma unroll
        for (int i = 0; i < 4; ++i)
            a[i] = *(const bf16x8*)&Xs[(wm * 64 + i * 16 + r) * 32 + qq * 8];
        #pragma unroll
        for (int j = 0; j < 4; ++j)
            b[j] = *(const bf16x8*)&Ws[(wn * 64 + j * 16 + r) * 32 + qq * 8];
        #pragma unroll
        for (int i = 0; i < 4; ++i)
            #pragma unroll
            for (int j = 0; j < 4; ++j)
                acc[i][j] = __builtin_amdgcn_mfma_f32_16x16x32_bf16(
                    a[i], b[j], acc[i][j], 0, 0, 0);
        __syncthreads();
    }
}

#define GEMM_PROLOGUE                                                        \
    __shared__ unsigned short Xs[4096];                                      \
    __shared__ unsigned short Ws[4096];                                      \
    const int tid  = threadIdx.x;                                            \
    const int wave = tid >> 6;                                               \
    const int lane = tid & 63;                                               \
    const int wm   = wave >> 1;                                              \
    const int wn   = wave & 1;                                               \
    const int qq   = lane >> 4;                                              \
    const int r    = lane & 15;                                              \
    f32x4 acc[4][4];                                                         \
    _Pragma("unroll")                                                        \
    for (int i = 0; i < 4; ++i)                                              \
        _Pragma("unroll")                                                    \
        for (int j = 0; j < 4; ++j)                                          \
            acc[i][j] = f32x4{0.f, 0.f, 0.f, 0.f};

// C/D layout: col = lane&15, row = (lane>>4)*4 + reg
#define EPILOGUE_LOOP(BODY)                                                  \
    _Pragma("unroll")                                                        \
    for (int i = 0; i < 4; ++i)                                              \
        _Pragma("unroll")                                                    \
        for (int j = 0; j < 4; ++j)                                          \
            _Pragma("unroll")                                                \
            for (int rr = 0; rr < 4; ++rr) {                                 \
                const int row = wm * 64 + i * 16 + qq * 4 + rr;              \
                const int col = wn * 64 + j * 16 + r;                        \
                const float val = acc[i][j][rr];                             \
                BODY                                                         \
            }

// ---------------------------------------------------------------------------
// fp32 -> bf16 conversion. Blocks 0..8191: X (2048 elems each).
// Blocks 8192..9727: W segments (512 blocks each).
// ---------------------------------------------------------------------------
__global__ __launch_bounds__(256) void to_bf16_all(
    const float* __restrict__ X, const float* __restrict__ Wq,
    const float* __restrict__ Wk, const float* __restrict__ Wv,
    unsigned short* __restrict__ Xb, unsigned short* __restrict__ Wb)
{
    const int bx = blockIdx.x;
    const float* src;
    unsigned short* dst;
    size_t off;
    if (bx < 8192) {
        src = X; dst = Xb; off = (size_t)bx * 2048;
    } else {
        const int s   = bx - 8192;
        const int seg = s >> 9;
        src = (seg == 0) ? Wq : (seg == 1) ? Wk : Wv;
        dst = Wb + (size_t)seg * (DA * DA);
        off = (size_t)(s & 511) * 2048;
    }
    const size_t i = off + (size_t)threadIdx.x * 8;
    const float4 v0 = *(const float4*)(src + i);
    const float4 v1 = *(const float4*)(src + i + 4);
    uint4 pk;
    pk.x = pack2(v0.x, v0.y); pk.y = pack2(v0.z, v0.w);
    pk.z = pack2(v1.x, v1.y); pk.w = pack2(v1.z, v1.w);
    *(uint4*)(dst + i) = pk;
}

// ---------------------------------------------------------------------------
// Projections. Wb = [3*1024][1024] (Wq|Wk|Wv). 3072 blocks, XCD-swizzled:
// xcd = li&7 owns m-tiles [xcd*16, xcd*16+16), iterating n fastest, so each
// X m-tile is fetched into exactly one XCD's L2 and reused 24x.
// ---------------------------------------------------------------------------
__global__ __launch_bounds__(256) void proj_gemm(
    const unsigned short* __restrict__ Xb, const unsigned short* __restrict__ Wb,
    unsigned short* __restrict__ qb, unsigned short* __restrict__ kb,
    unsigned short* __restrict__ vt)
{
    const int li   = blockIdx.x;
    const int xcd  = li & 7;
    const int slot = li >> 3;            // 0..383
    const int mt   = xcd * 16 + slot / 24;
    const int nt   = slot % 24;          // 0..23 across Wq|Wk|Wv
    const int m0   = mt * 128;
    const int n0w  = nt * 128;           // row in 3072-row Wb

    GEMM_PROLOGUE
    gemm_k_loop(Xb, DA, Wb, DA, m0, n0w, DA, Xs, Ws,
                tid, wm, wn, qq, r, acc);

    const int z  = nt >> 3;              // 0=Q 1=K 2=V
    const int nc = (nt & 7) * 128;       // col within 1024
    if (z < 2) {
        unsigned short* Y = z ? kb : qb;
        EPILOGUE_LOOP({
            Y[(size_t)(m0 + row) * DA + (nc + col)] = f2bf(val);
        })
    } else {
        EPILOGUE_LOOP({
            const int rg = m0 + row;
            const int bb = rg >> 12;
            const int tt = rg & 4095;
            vt[((size_t)bb << 22) + (size_t)(nc + col) * 4096 + tt] = f2bf(val);
        })
    }
}

// ---------------------------------------------------------------------------
// S = Q.K^T / 32, packed lower-tri. grid (32, 32, G), big-y first.
// ---------------------------------------------------------------------------
__global__ __launch_bounds__(256) void s_gemm(
    const unsigned short* __restrict__ qb, const unsigned short* __restrict__ kb,
    unsigned short* __restrict__ sbuf, int bbase)
{
    const int y = 31 - (int)blockIdx.y;
    const int x = blockIdx.x;
    if (x > y) return;
    const int b = bbase + blockIdx.z;
    const unsigned short* Qb = qb + (size_t)b * T_SEQ * DA;
    const unsigned short* Kb = kb + (size_t)b * T_SEQ * DA;

    GEMM_PROLOGUE
    gemm_k_loop(Qb, DA, Kb, DA, y * 128, x * 128, DA, Xs, Ws,
                tid, wm, wn, qq, r, acc);

    const int ld = (y + 1) * 128;
    unsigned short* base = sbuf + (size_t)blockIdx.z * SB_ELEMS
                         + (size_t)(y * (y + 1) / 2) * 16384;
    EPILOGUE_LOOP({
        base[(size_t)row * ld + (x * 128 + col)] = f2bf(val * 0.03125f);
    })
}

// ---------------------------------------------------------------------------
// Row softmax on packed S. grid (4096, G); big rows first.
// ---------------------------------------------------------------------------
__global__ __launch_bounds__(256) void softmax_rows(unsigned short* __restrict__ sbuf)
{
    __shared__ float row[4096];
    __shared__ float red[4];
    const int q   = 4095 - (int)blockIdx.x;
    const int n   = q + 1;
    const int tid = threadIdx.x;
    const int y   = q >> 7;
    const int ld  = (y + 1) * 128;
    unsigned short* rp = sbuf + (size_t)blockIdx.y * SB_ELEMS
                       + (size_t)(y * (y + 1) / 2) * 16384
                       + (size_t)(q & 127) * ld;
    const int n8 = n & ~7;

    for (int i0 = tid * 8; i0 < n8; i0 += 2048) {
        const uint4 v = *(const uint4*)(rp + i0);
        *(float4*)&row[i0]     = make_float4(bflo(v.x), bfhi(v.x), bflo(v.y), bfhi(v.y));
        *(float4*)&row[i0 + 4] = make_float4(bflo(v.z), bfhi(v.z), bflo(v.w), bfhi(v.w));
    }
    for (int i = n8 + tid; i < n; i += 256)
        row[i] = __builtin_bit_cast(float, (unsigned)rp[i] << 16);
    __syncthreads();

    float m = -1e30f;
    for (int i = tid; i < n; i += 256) m = fmaxf(m, row[i]);
    #pragma unroll
    for (int off = 32; off >= 1; off >>= 1) m = fmaxf(m, __shfl_xor(m, off, 64));
    if ((tid & 63) == 0) red[tid >> 6] = m;
    __syncthreads();
    m = fmaxf(fmaxf(red[0], red[1]), fmaxf(red[2], red[3]));
    __syncthreads();

    float s = 0.f;
    for (int i = tid; i < n; i += 256) {
        const float e = __expf(row[i] - m);
        row[i] = e;
        s += e;
    }
    #pragma unroll
    for (int off = 32; off >= 1; off >>= 1) s += __shfl_xor(s, off, 64);
    if ((tid & 63) == 0) red[tid >> 6] = s;
    __syncthreads();
    s = red[0] + red[1] + red[2] + red[3];
    const float inv = 1.f / s;

    for (int i0 = tid * 8; i0 < n8; i0 += 2048) {
        const float4 f0 = *(const float4*)&row[i0];
        const float4 f1 = *(const float4*)&row[i0 + 4];
        uint4 pk;
        pk.x = pack2(f0.x * inv, f0.y * inv);
        pk.y = pack2(f0.z * inv, f0.w * inv);
        pk.z = pack2(f1.x * inv, f1.y * inv);
        pk.w = pack2(f1.z * inv, f1.w * inv);
        *(uint4*)(rp + i0) = pk;
    }
    for (int i = n8 + tid; i < ld; i += 256)
        rp[i] = (i < n) ? f2bf(row[i] * inv) : (unsigned short)0;
}

// ---------------------------------------------------------------------------
// out = P.Vt^T, K = (y+1)*128. grid (8, 32, G), big-K first.
// ---------------------------------------------------------------------------
__global__ __launch_bounds__(256) void o_gemm(
    const unsigned short* __restrict__ sbuf, const unsigned short* __restrict__ vt,
    float* __restrict__ out, int bbase)
{
    const int y = 31 - (int)blockIdx.y;
    const int b = bbase + blockIdx.z;
    const int K_len = (y + 1) * 128;
    const unsigned short* A  = sbuf + (size_t)blockIdx.z * SB_ELEMS
                             + (size_t)(y * (y + 1) / 2) * 16384;
    const unsigned short* Bv = vt + (size_t)b * T_SEQ * DA;   // [1024][4096]
    const int n0 = blockIdx.x * 128;

    GEMM_PROLOGUE
    gemm_k_loop(A, K_len, Bv, T_SEQ, 0, n0, K_len, Xs, Ws,
                tid, wm, wn, qq, r, acc);

    float* outb = out + (size_t)b * T_SEQ * DA + (size_t)y * 128 * DA;
    EPILOGUE_LOOP({
        outb[(size_t)row * DA + (n0 + col)] = rintf(val * 1e4f) * 1e-4f;
    })
}

// ---------------------------------------------------------------------------
extern "C" void kernel_launch(void* const* d_in, const int* in_sizes, int n_in,
                              void* d_out, int out_size, void* d_ws, size_t ws_size,
                              hipStream_t stream)
{
    const float* X  = (const float*)d_in[0];
    const float* Wq = (const float*)d_in[1];
    const float* Wk = (const float*)d_in[2];
    const float* Wv = (const float*)d_in[3];
    float* out = (float*)d_out;

    unsigned short* qb   = (unsigned short*)d_ws;          // [16384,1024]
    unsigned short* kb   = qb + (size_t)M_TOT * DA;
    unsigned short* vt   = kb + (size_t)M_TOT * DA;        // [4][1024][4096]
    unsigned short* sbuf = vt + (size_t)M_TOT * DA;        // G * SB_ELEMS

    // bf16 copies of X / W live in d_out (64 MB), dead until o_gemm writes.
    unsigned short* Xb = (unsigned short*)d_out;           // 32 MB
    unsigned short* Wb = Xb + (size_t)M_TOT * DA;          // 6 MB ([3*1024][1024])

    const size_t fixed = (size_t)3 * M_TOT * DA * 2;
    int G = 1;
    if (ws_size >= fixed + (size_t)4 * SB_ELEMS * 2) G = 4;
    else if (ws_size >= fixed + (size_t)2 * SB_ELEMS * 2) G = 2;

    to_bf16_all<<<9728, 256, 0, stream>>>(X, Wq, Wk, Wv, Xb, Wb);
    proj_gemm<<<3072, 256, 0, stream>>>(Xb, Wb, qb, kb, vt);

    for (int b0 = 0; b0 < BATCH; b0 += G) {
        s_gemm<<<dim3(32, 32, G), 256, 0, stream>>>(qb, kb, sbuf, b0);
        softmax_rows<<<dim3(4096, G), 256, 0, stream>>>(sbuf);
        o_gemm<<<dim3(8, 32, G), 256, 0, stream>>>(sbuf, vt, out, b0);
    }
}